// Round 3
// baseline (458.364 us; speedup 1.0000x reference)
//
#include <hip/hip_runtime.h>

// Problem: B=4, N=512, RBF=32, F=16
// image   (B,N,N,32) f32   d_in[0]
// vectors (B,N,N,3)  f32   d_in[1]
// feat0   (B,N,16,1) f32   d_in[2]
// feat1   (B,N,16,3) f32   d_in[3]
// W00,b00,W01,b01,W10,b10,W11,b11  d_in[4..11]
// out: out1(B,N,16,1) | out2(B,N,16,3) | out3(B,N,16,3) | out4(B,N,16,1) | out5(B,N,16,3)
//
// Radial GEMM via mfma_f32_16x16x32_bf16 (A/B packed with the same k-slot
// convention -> contraction correct regardless of HW k mapping; C/D layout is
// the HW-verified col=lane&15, row=(lane>>4)*4+reg).
// Round 3: 2-deep register pipeline over 16-b tiles (ping-pong named Tile
// structs, all-static indexing) so each tile's ~36 loads are in flight under
// the previous tile's compute. Latency-bound fix per counter evidence
// (85us regardless of HBM traffic; VALUBusy 26%).

typedef __attribute__((ext_vector_type(8))) short short8;
typedef __attribute__((ext_vector_type(4))) float f32x4;

#define EPS2 1e-14f

static __device__ __forceinline__ short f2bf(float x) {
    unsigned int u = __float_as_uint(x);
    unsigned int r = (u + 0x7FFFu + ((u >> 16) & 1u)) >> 16;   // RNE
    return (short)r;
}

struct Tile {
    float4 a0, a1;                       // image row slice (pre-cvt)
    float vx[4], vy[4], vz[4];           // vectors per reg
    float f0v[4];                        // feat0 per reg
    float u0[4], u1[4], u2[4];           // feat1 per reg
};

struct Acc {
    float o1, o4;
    float o2x, o2y, o2z;
    float o3x, o3y, o3z;
    float o5x, o5y, o5z;
};

static __device__ __forceinline__ void load_tile(
    Tile& T, int b0, int g, int f,
    const float* __restrict__ imgbase, const float* __restrict__ vecbase,
    const float* __restrict__ f0base,  const float* __restrict__ f1base)
{
    const float* arow = imgbase + (size_t)(b0 + f) * 32 + g * 8;
    T.a0 = *(const float4*)(arow);
    T.a1 = *(const float4*)(arow + 4);
    #pragma unroll
    for (int reg = 0; reg < 4; ++reg) {
        const int b = b0 + 4 * g + reg;
        const float* vp = vecbase + b * 3;
        T.vx[reg] = vp[0];
        T.vy[reg] = vp[1];
        T.vz[reg] = vp[2];
        T.f0v[reg] = f0base[b * 16 + f];
        const float* f1p = f1base + (size_t)(b * 16 + f) * 3;
        T.u0[reg] = f1p[0];
        T.u1[reg] = f1p[1];
        T.u2[reg] = f1p[2];
    }
}

static __device__ __forceinline__ void compute_tile(
    const Tile& T, Acc& A,
    const short8& wf0, const short8& wf1, const short8& wf2, const short8& wf3,
    float bias0, float bias1, float bias2, float bias3)
{
    short8 af;
    af[0] = f2bf(T.a0.x); af[1] = f2bf(T.a0.y);
    af[2] = f2bf(T.a0.z); af[3] = f2bf(T.a0.w);
    af[4] = f2bf(T.a1.x); af[5] = f2bf(T.a1.y);
    af[6] = f2bf(T.a1.z); af[7] = f2bf(T.a1.w);

    f32x4 d0 = {0.f, 0.f, 0.f, 0.f};
    f32x4 d1 = {0.f, 0.f, 0.f, 0.f};
    f32x4 d2 = {0.f, 0.f, 0.f, 0.f};
    f32x4 d3 = {0.f, 0.f, 0.f, 0.f};
    d0 = __builtin_amdgcn_mfma_f32_16x16x32_bf16(af, wf0, d0, 0, 0, 0);
    d1 = __builtin_amdgcn_mfma_f32_16x16x32_bf16(af, wf1, d1, 0, 0, 0);
    d2 = __builtin_amdgcn_mfma_f32_16x16x32_bf16(af, wf2, d2, 0, 0, 0);
    d3 = __builtin_amdgcn_mfma_f32_16x16x32_bf16(af, wf3, d3, 0, 0, 0);

    #pragma unroll
    for (int reg = 0; reg < 4; ++reg) {
        const float vx = T.vx[reg], vy = T.vy[reg], vz = T.vz[reg];
        const float n2 = vx * vx + vy * vy + vz * vz;
        const bool keep = n2 >= EPS2;

        const float f0v = T.f0v[reg];
        const float u0 = T.u0[reg], u1 = T.u1[reg], u2 = T.u2[reg];

        const float r00 = d0[reg] + bias0;
        const float r01 = keep ? (d1[reg] + bias1) : 0.f;
        const float r10 = d2[reg] + bias2;
        const float r11 = keep ? (d3[reg] + bias3) : 0.f;

        A.o1 = fmaf(r00, f0v, A.o1);
        const float t01 = r01 * f0v;
        A.o2x = fmaf(t01, vx, A.o2x);
        A.o2y = fmaf(t01, vy, A.o2y);
        A.o2z = fmaf(t01, vz, A.o2z);
        A.o3x = fmaf(r10, u0, A.o3x);
        A.o3y = fmaf(r10, u1, A.o3y);
        A.o3z = fmaf(r10, u2, A.o3z);
        const float d = fmaf(vx, u0, fmaf(vy, u1, vz * u2));
        A.o4 = fmaf(r11, d, A.o4);
        const float c0 = vy * u2 - vz * u1;
        const float c1 = vz * u0 - vx * u2;
        const float c2 = vx * u1 - vy * u0;
        A.o5x = fmaf(r11, c0, A.o5x);
        A.o5y = fmaf(r11, c1, A.o5y);
        A.o5z = fmaf(r11, c2, A.o5z);
    }
}

__global__ __launch_bounds__(256, 4) void conv_mfma_pipe_kernel(
    const float* __restrict__ image,
    const float* __restrict__ vectors,
    const float* __restrict__ feat0,
    const float* __restrict__ feat1,
    const float* __restrict__ W00, const float* __restrict__ b00,
    const float* __restrict__ W01, const float* __restrict__ b01,
    const float* __restrict__ W10, const float* __restrict__ b10,
    const float* __restrict__ W11, const float* __restrict__ b11,
    float* __restrict__ out)
{
    __shared__ float red[4][16][12];     // [wave][f][comp(11 pad 12)]

    const int t    = threadIdx.x;
    const int wave = t >> 6;
    const int lane = t & 63;
    const int f    = lane & 15;          // B col / D col
    const int g    = lane >> 4;          // k-group (A/B), row-group (D)
    const int ma   = blockIdx.x;         // m*512 + a
    const int m    = ma >> 9;

    // ---- weight fragments (VGPR-resident, once per block) ----
    short8 wf0, wf1, wf2, wf3;
    float bias0, bias1, bias2, bias3;
    {
        #pragma unroll
        for (int j = 0; j < 8; ++j) {
            const int k = g * 8 + j;
            wf0[j] = f2bf(W00[k * 16 + f]);
            wf1[j] = f2bf(W01[k * 16 + f]);
            wf2[j] = f2bf(W10[k * 16 + f]);
            wf3[j] = f2bf(W11[k * 16 + f]);
        }
        bias0 = b00[f]; bias1 = b01[f]; bias2 = b10[f]; bias3 = b11[f];
    }

    const float* imgbase = image   + (size_t)ma * (512 * 32);
    const float* vecbase = vectors + (size_t)ma * (512 * 3);
    const float* f0base  = feat0   + (size_t)m  * (512 * 16);
    const float* f1base  = feat1   + (size_t)m  * (512 * 16 * 3);

    Acc A = {0.f, 0.f, 0.f, 0.f, 0.f, 0.f, 0.f, 0.f, 0.f, 0.f, 0.f};

    const int bbase = wave * 128;        // wave's b range: [bbase, bbase+128)

    Tile TA, TB;
    load_tile(TA, bbase, g, f, imgbase, vecbase, f0base, f1base);

    for (int tt = 0; tt < 8; tt += 2) {
        load_tile(TB, bbase + (tt + 1) * 16, g, f, imgbase, vecbase, f0base, f1base);
        compute_tile(TA, A, wf0, wf1, wf2, wf3, bias0, bias1, bias2, bias3);
        if (tt + 2 < 8)
            load_tile(TA, bbase + (tt + 2) * 16, g, f, imgbase, vecbase, f0base, f1base);
        compute_tile(TB, A, wf0, wf1, wf2, wf3, bias0, bias1, bias2, bias3);
    }

    // ---- in-wave reduce over the 4 lane-groups sharing f ----
    #define WRED(x) x += __shfl_xor(x, 16); x += __shfl_xor(x, 32);
    WRED(A.o1)  WRED(A.o2x) WRED(A.o2y) WRED(A.o2z)
    WRED(A.o3x) WRED(A.o3y) WRED(A.o3z) WRED(A.o4)
    WRED(A.o5x) WRED(A.o5y) WRED(A.o5z)
    #undef WRED

    if (lane < 16) {
        red[wave][f][0]  = A.o1;
        red[wave][f][1]  = A.o2x;
        red[wave][f][2]  = A.o2y;
        red[wave][f][3]  = A.o2z;
        red[wave][f][4]  = A.o3x;
        red[wave][f][5]  = A.o3y;
        red[wave][f][6]  = A.o3z;
        red[wave][f][7]  = A.o4;
        red[wave][f][8]  = A.o5x;
        red[wave][f][9]  = A.o5y;
        red[wave][f][10] = A.o5z;
    }
    __syncthreads();

    if (t < 176) {
        const int ff = t / 11;
        const int comp = t % 11;
        float s = red[0][ff][comp] + red[1][ff][comp]
                + red[2][ff][comp] + red[3][ff][comp];

        const size_t base16 = (size_t)ma * 16 + ff;
        const size_t base48 = base16 * 3;
        if (comp == 0)      out[base16] = s;
        else if (comp < 4)  out[32768  + base48 + (comp - 1)] = s;
        else if (comp < 7)  out[131072 + base48 + (comp - 4)] = s;
        else if (comp == 7) out[229376 + base16] = s;
        else                out[262144 + base48 + (comp - 8)] = s;
    }
}

extern "C" void kernel_launch(void* const* d_in, const int* in_sizes, int n_in,
                              void* d_out, int out_size, void* d_ws, size_t ws_size,
                              hipStream_t stream) {
    const float* image   = (const float*)d_in[0];
    const float* vectors = (const float*)d_in[1];
    const float* feat0   = (const float*)d_in[2];
    const float* feat1   = (const float*)d_in[3];
    const float* W00 = (const float*)d_in[4];
    const float* b00 = (const float*)d_in[5];
    const float* W01 = (const float*)d_in[6];
    const float* b01 = (const float*)d_in[7];
    const float* W10 = (const float*)d_in[8];
    const float* b10 = (const float*)d_in[9];
    const float* W11 = (const float*)d_in[10];
    const float* b11 = (const float*)d_in[11];
    float* out = (float*)d_out;

    conv_mfma_pipe_kernel<<<4 * 512, 256, 0, stream>>>(
        image, vectors, feat0, feat1,
        W00, b00, W01, b01, W10, b10, W11, b11, out);
}

// Round 4
// 303.874 us; speedup vs baseline: 1.5084x; 1.5084x over previous
//
#include <hip/hip_runtime.h>

// Problem: B=4, N=512, RBF=32, F=16
// image   (B,N,N,32) f32   d_in[0]
// vectors (B,N,N,3)  f32   d_in[1]
// feat0   (B,N,16,1) f32   d_in[2]
// feat1   (B,N,16,3) f32   d_in[3]
// W00,b00,W01,b01,W10,b10,W11,b11  d_in[4..11]
// out: out1(B,N,16,1) | out2(B,N,16,3) | out3(B,N,16,3) | out4(B,N,16,1) | out5(B,N,16,3)
//
// Round 4: round-2 skeleton (85us, known-good) + 2-deep register pipeline done
// with ONLY named scalars/float4s stamped by macro (no structs/arrays -> no
// scratch; round 3's 500MB WRITE_SIZE was struct-of-arrays spill).
// vectors tail vectorized: lane's 4 consecutive b's = 12 contiguous aligned
// floats = 3x float4.

typedef __attribute__((ext_vector_type(8))) short short8;
typedef __attribute__((ext_vector_type(4))) float f32x4;

#define EPS2 1e-14f

static __device__ __forceinline__ short f2bf(float x) {
    unsigned int u = __float_as_uint(x);
    unsigned int r = (u + 0x7FFFu + ((u >> 16) & 1u)) >> 16;   // RNE
    return (short)r;
}

__global__ __launch_bounds__(256, 3) void conv_mfma_pipe2_kernel(
    const float* __restrict__ image,
    const float* __restrict__ vectors,
    const float* __restrict__ feat0,
    const float* __restrict__ feat1,
    const float* __restrict__ W00, const float* __restrict__ b00,
    const float* __restrict__ W01, const float* __restrict__ b01,
    const float* __restrict__ W10, const float* __restrict__ b10,
    const float* __restrict__ W11, const float* __restrict__ b11,
    float* __restrict__ out)
{
    __shared__ float red[4][16][12];     // [wave][f][comp(11 pad 12)]

    const int t    = threadIdx.x;
    const int wave = t >> 6;
    const int lane = t & 63;
    const int f    = lane & 15;          // B col / D col
    const int g    = lane >> 4;          // k-group (A/B), row-group (D)
    const int ma   = blockIdx.x;         // m*512 + a
    const int m    = ma >> 9;

    // ---- weight fragments (VGPR-resident, once per block) ----
    short8 wf0, wf1, wf2, wf3;
    float bias0, bias1, bias2, bias3;
    {
        #pragma unroll
        for (int j = 0; j < 8; ++j) {
            const int k = g * 8 + j;
            wf0[j] = f2bf(W00[k * 16 + f]);
            wf1[j] = f2bf(W01[k * 16 + f]);
            wf2[j] = f2bf(W10[k * 16 + f]);
            wf3[j] = f2bf(W11[k * 16 + f]);
        }
        bias0 = b00[f]; bias1 = b01[f]; bias2 = b10[f]; bias3 = b11[f];
    }

    const float* imgbase = image   + (size_t)ma * (512 * 32);
    const float* vecbase = vectors + (size_t)ma * (512 * 3);
    const float* f0base  = feat0   + (size_t)m  * (512 * 16);
    const float* f1base  = feat1   + (size_t)m  * (512 * 16 * 3);

    float acc1 = 0.f, acc4 = 0.f;
    float acc2x = 0.f, acc2y = 0.f, acc2z = 0.f;
    float acc3x = 0.f, acc3y = 0.f, acc3z = 0.f;
    float acc5x = 0.f, acc5y = 0.f, acc5z = 0.f;

    const int bbase = wave * 128;        // wave's b range: [bbase, bbase+128)

    // ================= banked pipeline (named vars only) =================
#define DECL_BANK(S) \
    float4 A0##S, A1##S, V0##S, V1##S, V2##S; \
    float F0a##S, F0b##S, F0c##S, F0d##S; \
    float P00##S, P01##S, P02##S, P10##S, P11##S, P12##S; \
    float P20##S, P21##S, P22##S, P30##S, P31##S, P32##S;

#define LOAD_BANK(S, B0) { \
    const float* arow_ = imgbase + (size_t)((B0) + f) * 32 + g * 8; \
    A0##S = *(const float4*)(arow_); \
    A1##S = *(const float4*)(arow_ + 4); \
    const int bb_ = (B0) + 4 * g; \
    const float* vp_ = vecbase + bb_ * 3; \
    V0##S = *(const float4*)(vp_); \
    V1##S = *(const float4*)(vp_ + 4); \
    V2##S = *(const float4*)(vp_ + 8); \
    const float* f0p_ = f0base + bb_ * 16 + f; \
    F0a##S = f0p_[0]; F0b##S = f0p_[16]; F0c##S = f0p_[32]; F0d##S = f0p_[48]; \
    const float* f1p_ = f1base + (size_t)(bb_ * 16 + f) * 3; \
    P00##S = f1p_[0];   P01##S = f1p_[1];   P02##S = f1p_[2]; \
    P10##S = f1p_[48];  P11##S = f1p_[49];  P12##S = f1p_[50]; \
    P20##S = f1p_[96];  P21##S = f1p_[97];  P22##S = f1p_[98]; \
    P30##S = f1p_[144]; P31##S = f1p_[145]; P32##S = f1p_[146]; \
}

#define TAIL(R00, R01, R10, R11, VX, VY, VZ, F0V, U0, U1, U2) { \
    const float vx_ = (VX), vy_ = (VY), vz_ = (VZ); \
    const float n2_ = vx_ * vx_ + vy_ * vy_ + vz_ * vz_; \
    const bool keep_ = n2_ >= EPS2; \
    const float r00_ = (R00) + bias0; \
    const float r01_ = keep_ ? ((R01) + bias1) : 0.f; \
    const float r10_ = (R10) + bias2; \
    const float r11_ = keep_ ? ((R11) + bias3) : 0.f; \
    const float f0v_ = (F0V); \
    const float u0_ = (U0), u1_ = (U1), u2_ = (U2); \
    acc1 = fmaf(r00_, f0v_, acc1); \
    const float t01_ = r01_ * f0v_; \
    acc2x = fmaf(t01_, vx_, acc2x); \
    acc2y = fmaf(t01_, vy_, acc2y); \
    acc2z = fmaf(t01_, vz_, acc2z); \
    acc3x = fmaf(r10_, u0_, acc3x); \
    acc3y = fmaf(r10_, u1_, acc3y); \
    acc3z = fmaf(r10_, u2_, acc3z); \
    const float dd_ = fmaf(vx_, u0_, fmaf(vy_, u1_, vz_ * u2_)); \
    acc4 = fmaf(r11_, dd_, acc4); \
    acc5x = fmaf(r11_, vy_ * u2_ - vz_ * u1_, acc5x); \
    acc5y = fmaf(r11_, vz_ * u0_ - vx_ * u2_, acc5y); \
    acc5z = fmaf(r11_, vx_ * u1_ - vy_ * u0_, acc5z); \
}

#define COMPUTE_BANK(S) { \
    short8 af_; \
    af_[0] = f2bf(A0##S.x); af_[1] = f2bf(A0##S.y); \
    af_[2] = f2bf(A0##S.z); af_[3] = f2bf(A0##S.w); \
    af_[4] = f2bf(A1##S.x); af_[5] = f2bf(A1##S.y); \
    af_[6] = f2bf(A1##S.z); af_[7] = f2bf(A1##S.w); \
    f32x4 d0_ = {0.f, 0.f, 0.f, 0.f}; \
    f32x4 d1_ = {0.f, 0.f, 0.f, 0.f}; \
    f32x4 d2_ = {0.f, 0.f, 0.f, 0.f}; \
    f32x4 d3_ = {0.f, 0.f, 0.f, 0.f}; \
    d0_ = __builtin_amdgcn_mfma_f32_16x16x32_bf16(af_, wf0, d0_, 0, 0, 0); \
    d1_ = __builtin_amdgcn_mfma_f32_16x16x32_bf16(af_, wf1, d1_, 0, 0, 0); \
    d2_ = __builtin_amdgcn_mfma_f32_16x16x32_bf16(af_, wf2, d2_, 0, 0, 0); \
    d3_ = __builtin_amdgcn_mfma_f32_16x16x32_bf16(af_, wf3, d3_, 0, 0, 0); \
    TAIL(d0_[0], d1_[0], d2_[0], d3_[0], V0##S.x, V0##S.y, V0##S.z, F0a##S, P00##S, P01##S, P02##S) \
    TAIL(d0_[1], d1_[1], d2_[1], d3_[1], V0##S.w, V1##S.x, V1##S.y, F0b##S, P10##S, P11##S, P12##S) \
    TAIL(d0_[2], d1_[2], d2_[2], d3_[2], V1##S.z, V1##S.w, V2##S.x, F0c##S, P20##S, P21##S, P22##S) \
    TAIL(d0_[3], d1_[3], d2_[3], d3_[3], V2##S.y, V2##S.z, V2##S.w, F0d##S, P30##S, P31##S, P32##S) \
}

    DECL_BANK(A)
    DECL_BANK(B)

    LOAD_BANK(A, bbase +   0)
    LOAD_BANK(B, bbase +  16)
    COMPUTE_BANK(A)
    LOAD_BANK(A, bbase +  32)
    COMPUTE_BANK(B)
    LOAD_BANK(B, bbase +  48)
    COMPUTE_BANK(A)
    LOAD_BANK(A, bbase +  64)
    COMPUTE_BANK(B)
    LOAD_BANK(B, bbase +  80)
    COMPUTE_BANK(A)
    LOAD_BANK(A, bbase +  96)
    COMPUTE_BANK(B)
    LOAD_BANK(B, bbase + 112)
    COMPUTE_BANK(A)
    COMPUTE_BANK(B)

#undef DECL_BANK
#undef LOAD_BANK
#undef TAIL
#undef COMPUTE_BANK

    // ---- in-wave reduce over the 4 lane-groups sharing f ----
    #define WRED(x) x += __shfl_xor(x, 16); x += __shfl_xor(x, 32);
    WRED(acc1)  WRED(acc2x) WRED(acc2y) WRED(acc2z)
    WRED(acc3x) WRED(acc3y) WRED(acc3z) WRED(acc4)
    WRED(acc5x) WRED(acc5y) WRED(acc5z)
    #undef WRED

    if (lane < 16) {
        red[wave][f][0]  = acc1;
        red[wave][f][1]  = acc2x;
        red[wave][f][2]  = acc2y;
        red[wave][f][3]  = acc2z;
        red[wave][f][4]  = acc3x;
        red[wave][f][5]  = acc3y;
        red[wave][f][6]  = acc3z;
        red[wave][f][7]  = acc4;
        red[wave][f][8]  = acc5x;
        red[wave][f][9]  = acc5y;
        red[wave][f][10] = acc5z;
    }
    __syncthreads();

    if (t < 176) {
        const int ff = t / 11;
        const int comp = t % 11;
        float s = red[0][ff][comp] + red[1][ff][comp]
                + red[2][ff][comp] + red[3][ff][comp];

        const size_t base16 = (size_t)ma * 16 + ff;
        const size_t base48 = base16 * 3;
        if (comp == 0)      out[base16] = s;
        else if (comp < 4)  out[32768  + base48 + (comp - 1)] = s;
        else if (comp < 7)  out[131072 + base48 + (comp - 4)] = s;
        else if (comp == 7) out[229376 + base16] = s;
        else                out[262144 + base48 + (comp - 8)] = s;
    }
}

extern "C" void kernel_launch(void* const* d_in, const int* in_sizes, int n_in,
                              void* d_out, int out_size, void* d_ws, size_t ws_size,
                              hipStream_t stream) {
    const float* image   = (const float*)d_in[0];
    const float* vectors = (const float*)d_in[1];
    const float* feat0   = (const float*)d_in[2];
    const float* feat1   = (const float*)d_in[3];
    const float* W00 = (const float*)d_in[4];
    const float* b00 = (const float*)d_in[5];
    const float* W01 = (const float*)d_in[6];
    const float* b01 = (const float*)d_in[7];
    const float* W10 = (const float*)d_in[8];
    const float* b10 = (const float*)d_in[9];
    const float* W11 = (const float*)d_in[10];
    const float* b11 = (const float*)d_in[11];
    float* out = (float*)d_out;

    conv_mfma_pipe2_kernel<<<4 * 512, 256, 0, stream>>>(
        image, vectors, feat0, feat1,
        W00, b00, W01, b01, W10, b10, W11, b11, out);
}